// Round 14
// baseline (808.842 us; speedup 1.0000x reference)
//
#include <hip/hip_runtime.h>
#include <hip/hip_bf16.h>

#define NP   19
#define EPB  16
#define BLK  256
#define RSTRIDE 4864
#define WS   24            // w/n stride within an edge row (bf16 units); 48B -> 2-way free
#define ES   392           // e stride (bf16): 16*24 + 8, keeps 16B align + bank spread
#define PBS  (16*ES)       // single staging buffer stride (bf16 units)

typedef __attribute__((ext_vector_type(8))) short bf16x8;
typedef __attribute__((ext_vector_type(4))) float f32x4;

// ---- per-path metadata (p wave-uniform -> scalar loads) ----
__device__ const int   d_io[NP]  = {0,0,0, 1,1,1,1,1,1,1, 2,2,2,2, 2,2,2,2,2};
__device__ const int   d_ii[NP]  = {0,1,2, 0,1,1,1,2,2,2, 0,1,1,1, 2,2,2,2,2};
__device__ const int   d_lf[NP]  = {0,1,2, 1,0,1,2,1,2,3, 2,1,2,3, 0,1,2,3,4};
__device__ const int   d_cgb[NP] = {0,1,10, 35,44,53,80,125,170,245, 350,375,420,495, 600,625,700,825,1000};
__device__ const float d_nrm5[5] = {1.0f, 0.57735026918962576f, 0.44721359549995794f,
                                    0.37796447300922722f, 0.33333333333333333f};

__device__ __forceinline__ unsigned short to_bf16(float v) {
    __hip_bfloat16 h = __float2bfloat16(v);
    return *reinterpret_cast<unsigned short*>(&h);
}

// ---- setup: swizzle R into MFMA fragment order, bf16, K 10->32 zero-padded ----
__global__ void k_rt(const float* __restrict__ R, unsigned short* __restrict__ Rt) {
    int i = blockIdx.x * blockDim.x + threadIdx.x;     // over NP*16*64*8
    if (i >= NP * 16 * 64 * 8) return;
    const int j    = i & 7;
    const int lane = (i >> 3) & 63;
    const int t    = (i >> 9) & 15;
    const int p    = i >> 13;
    const int r    = (lane >> 4) * 8 + j;
    const int col  = p * 256 + 16 * t + (lane & 15);
    float v = (r < 10) ? R[r * RSTRIDE + col] : 0.f;
    Rt[i] = to_bf16(v);
}

// ---------------- Phase A: edge-major; one path per staging round ----------------
__global__ __launch_bounds__(BLK, 5)
void se3_msg(const float* __restrict__ F,
             const float* __restrict__ Ys, const float* __restrict__ Rad,
             const float* __restrict__ cg, const unsigned short* __restrict__ Rt,
             const int* __restrict__ Mb,
             float* __restrict__ msg, const int nE)
{
    __shared__ __align__(16) unsigned short s_Wa[PBS];   // Wstack A-frag  [e][w][v]
    __shared__ __align__(16) unsigned short s_tB[PBS];   // tmpstack B-frag [e][n][v]
    __shared__ float s_cgy[EPB][40];                     // cgY, o-rows padded to 8

    const int tid  = threadIdx.x;
    const int l    = tid & 15;
    const int eloc = tid >> 4;
    const int lane = tid & 63;
    const int wv   = tid >> 6;
    const int q    = lane >> 4;
    const int n16  = lane & 15;
    const int e    = blockIdx.x * EPB + eloc;
    const bool act = (e < nE);
    const int  es  = act ? e : 0;

    // F slice -> registers (compile-time indexed)
    float fv[9];
    {
        const int b = Mb[es];
        const float* Fb = F + (size_t)b * 144;
        fv[0] = Fb[l];
        #pragma unroll
        for (int i = 0; i < 3; ++i) fv[1 + i] = Fb[16 + l*3 + i];
        #pragma unroll
        for (int i = 0; i < 5; ++i) fv[4 + i] = Fb[64 + l*5 + i];
    }
    // Ys row -> registers
    float y[25];
    {
        const float* yr = Ys + (size_t)es * 25;
        #pragma unroll
        for (int k = 0; k < 25; ++k) y[k] = yr[k];
    }
    // radii fragment (B operand of MFMA-1): B[k=r][n=e], K zero-padded 10->32
    bf16x8 radfrag;
    {
        const int m  = n16;
        const int k0 = q * 8;
        const int ge = blockIdx.x * EPB + m;
        const bool a = (ge < nE);
        const float* rp = Rad + (size_t)(a ? ge : 0) * 10;
        #pragma unroll
        for (int j = 0; j < 8; ++j) {
            const int k = k0 + j;
            radfrag[j] = (short)((a && k < 10) ? to_bf16(rp[k]) : (unsigned short)0);
        }
    }

    // tb one-time zero (maintained incrementally afterwards)
    {
        unsigned short* tb0 = &s_tB[eloc*ES + l];
        #pragma unroll
        for (int n = 0; n < 16; ++n) tb0[n*WS] = 0;
    }

    f32x4 D[4];
    #pragma unroll
    for (int ee = 0; ee < 4; ++ee) D[ee] = (f32x4){0.f,0.f,0.f,0.f};

    const bf16x8 ZF = {0,0,0,0,0,0,0,0};

    // ---- path loop: stage one path, one masked K=32 MFMA-2 step ----
    #pragma unroll 1
    for (int p = 0; p < NP; ++p) {
        // MFMA-1 (swapped): D = R_p^T(16c x 32k) @ rad^T(32k x 16e)
        // D[row=v=q*4+r][col=e=n16] -> b64 pack into A-layout [e][w][v].
        {
            const unsigned short* rtp = Rt + ((size_t)p*16 + 4*wv)*512 + lane*8;
            #pragma unroll
            for (int tt = 0; tt < 4; ++tt) {
                const bf16x8 rfrag = *reinterpret_cast<const bf16x8*>(rtp + tt*512);
                f32x4 d = __builtin_amdgcn_mfma_f32_16x16x32_bf16(
                              rfrag, radfrag, (f32x4){0.f,0.f,0.f,0.f}, 0, 0, 0);
                short4 pk;
                pk.x = (short)to_bf16(d[0]); pk.y = (short)to_bf16(d[1]);
                pk.z = (short)to_bf16(d[2]); pk.w = (short)to_bf16(d[3]);
                *reinterpret_cast<short4*>(
                    &s_Wa[n16*ES + (4*wv + tt)*WS + q*4]) = pk;
            }
        }

        // path metadata (scalar)
        const int io = d_io[p], ii = d_ii[p], lf = d_lf[p], cgb = d_cgb[p];
        const int dO = 2*io + 1, dI = 2*ii + 1, dF = 2*lf + 1;
        const int nOI = dO * dI;
        const int ob  = (io == 0) ? 0 : (io == 1) ? 1 : 4;
        const float nrm = d_nrm5[lf];

        // cgY cooperative (16 lanes of eloc); cg from global (L1-hot);
        // store at [o*8+i] so tmp stage can read o-rows as float4.
        for (int j0 = 0; j0 < nOI; j0 += 16) {
            const int j = j0 + l;
            if (j < nOI) {
                int o, i;
                if (dI == 1)      { o = j;     i = 0;         }
                else if (dI == 3) { o = j / 3; i = j - 3*o;   }
                else              { o = j / 5; i = j - 5*o;   }
                const float* cgp = cg + cgb + j*dF;
                float s;
                switch (lf) {   // wave-uniform
                  case 0:  s = cgp[0]*y[0]; break;
                  case 1:  s = cgp[0]*y[1]+cgp[1]*y[2]+cgp[2]*y[3]; break;
                  case 2:  s = cgp[0]*y[4]+cgp[1]*y[5]+cgp[2]*y[6]+cgp[3]*y[7]
                             + cgp[4]*y[8]; break;
                  case 3:  s = cgp[0]*y[9]+cgp[1]*y[10]+cgp[2]*y[11]+cgp[3]*y[12]
                             + cgp[4]*y[13]+cgp[5]*y[14]+cgp[6]*y[15]; break;
                  default: s = cgp[0]*y[16]+cgp[1]*y[17]+cgp[2]*y[18]+cgp[3]*y[19]
                             + cgp[4]*y[20]+cgp[5]*y[21]+cgp[6]*y[22]+cgp[7]*y[23]
                             + cgp[8]*y[24]; break;
                }
                s_cgy[eloc][o*8 + i] = s * nrm;
            }
        }
        __asm__ volatile("" ::: "memory");   // cgY visible (intra-wave exchange)

        // tmp[v=l, o] -> B-frag bf16 [e][n=ob+o][v]; zero only vacated slots
        {
            unsigned short* tb = &s_tB[eloc*ES + l];
            if (p == 3)       { tb[0] = 0; }
            else if (p == 10) { tb[WS] = 0; tb[2*WS] = 0; tb[3*WS] = 0; }
            if (ii == 0) {
                for (int o = 0; o < dO; ++o) {
                    const float c0 = s_cgy[eloc][o*8];
                    tb[(ob + o)*WS] = to_bf16(fv[0]*c0);
                }
            } else if (ii == 1) {
                for (int o = 0; o < dO; ++o) {
                    const float4 c4 = *reinterpret_cast<const float4*>(&s_cgy[eloc][o*8]);
                    tb[(ob + o)*WS] = to_bf16(fv[1]*c4.x + fv[2]*c4.y + fv[3]*c4.z);
                }
            } else {
                for (int o = 0; o < dO; ++o) {
                    const float4 c4 = *reinterpret_cast<const float4*>(&s_cgy[eloc][o*8]);
                    const float c4e = s_cgy[eloc][o*8 + 4];
                    tb[(ob + o)*WS] = to_bf16(fv[4]*c4.x + fv[5]*c4.y + fv[6]*c4.z
                                            + fv[7]*c4.w + fv[8]*c4e);
                }
            }
        }
        __asm__ volatile("" ::: "memory");
        __syncthreads();   // W (cross-wave w-tiles) + tmp staged for this path

        // MFMA-2 K-step (masked): msg_e(16w x 16n) += Wstack_e(16x16) @ tmpstack_e(16x16)
        // K=32 frag: k=q*8+j -> v for q<2; q>=2 half is hard-zero (exact).
        {
            #pragma unroll
            for (int ee = 0; ee < 4; ++ee) {
                const int eK = 4*wv + ee;
                bf16x8 Af = ZF, Bf = ZF;
                if (q < 2) {
                    Af = *reinterpret_cast<const bf16x8*>(
                             &s_Wa[eK*ES + n16*WS + q*8]);
                    Bf = *reinterpret_cast<const bf16x8*>(
                             &s_tB[eK*ES + n16*WS + q*8]);
                }
                D[ee] = __builtin_amdgcn_mfma_f32_16x16x32_bf16(Af, Bf, D[ee], 0, 0, 0);
            }
        }
        __syncthreads();   // WAR: next path rewrites s_Wa/s_tB
    }

    // epilogue: D[row=w=q*4+r, col=oflat=n16] -> msg[e][oflat*16 + w], float4 stores
    if (n16 < 9) {
        #pragma unroll
        for (int ee = 0; ee < 4; ++ee) {
            const int eg = blockIdx.x * EPB + 4*wv + ee;
            if (eg < nE) {
                float* mp = msg + (size_t)eg * 144 + n16*16 + q*4;
                float4 v4; v4.x = D[ee][0]; v4.y = D[ee][1]; v4.z = D[ee][2]; v4.w = D[ee][3];
                *reinterpret_cast<float4*>(mp) = v4;
            }
        }
    }
}

// ---------------- Phase B: node gather-reduce (no atomics) ----------------
__global__ __launch_bounds__(BLK)
void se3_gather(const float* __restrict__ msg, const int* __restrict__ off,
                const int* __restrict__ eidx, const float* __restrict__ Nn,
                float* __restrict__ Out, const int nN)
{
    const int l = threadIdx.x & 15;
    const int g = threadIdx.x >> 4;
    const int n = blockIdx.x * 16 + g;
    if (n >= nN) return;

    const int i0 = off[n], i1 = off[n + 1];
    float s[9];
    #pragma unroll
    for (int j = 0; j < 9; ++j) s[j] = 0.f;

    for (int idx = i0; idx < i1; ++idx) {
        const int eid = eidx[idx];
        const float* m = msg + (size_t)eid * 144 + l;
        #pragma unroll
        for (int j = 0; j < 9; ++j) s[j] += m[j * 16];
    }

    const float nn = Nn[n];
    float* orow = Out + (size_t)n * 144;
    orow[l] = s[0] * nn;
    #pragma unroll
    for (int o = 0; o < 3; ++o) orow[16 + l*3 + o] = s[1+o] * nn;
    #pragma unroll
    for (int o = 0; o < 5; ++o) orow[64 + l*5 + o] = s[4+o] * nn;
}

// ---------------- CSR build (by destination) ----------------
__global__ void k_count(const int* __restrict__ Ma, int* __restrict__ cur, int E) {
    int e = blockIdx.x * blockDim.x + threadIdx.x;
    if (e < E) atomicAdd(&cur[Ma[e]], 1);
}

__global__ void k_scan(int* __restrict__ cur, int* __restrict__ off, int N) {
    __shared__ int part[BLK];
    const int t = threadIdx.x;
    const int K = (N + BLK - 1) / BLK;
    const int i0 = t * K, i1 = min(i0 + K, N);
    int s = 0;
    for (int i = i0; i < i1; ++i) s += cur[i];
    part[t] = s;
    __syncthreads();
    if (t == 0) {
        int a = 0;
        for (int j = 0; j < BLK; ++j) { int v = part[j]; part[j] = a; a += v; }
        off[N] = a;
    }
    __syncthreads();
    int a = part[t];
    for (int i = i0; i < i1; ++i) {
        int v = cur[i];
        off[i] = a;
        cur[i] = a;       // reuse as scatter cursor
        a += v;
    }
}

__global__ void k_scatter(const int* __restrict__ Ma, int* __restrict__ cur,
                          int* __restrict__ eidx, int E) {
    int e = blockIdx.x * blockDim.x + threadIdx.x;
    if (e < E) {
        int pos = atomicAdd(&cur[Ma[e]], 1);
        eidx[pos] = e;
    }
}

extern "C" void kernel_launch(void* const* d_in, const int* in_sizes, int n_in,
                              void* d_out, int out_size, void* d_ws, size_t ws_size,
                              hipStream_t stream) {
    const float* F   = (const float*)d_in[0];
    const float* R   = (const float*)d_in[1];
    const float* Ys  = (const float*)d_in[2];
    const float* Rad = (const float*)d_in[3];
    const float* cg  = (const float*)d_in[4];
    const float* Nn  = (const float*)d_in[5];
    const int*   Ma  = (const int*)d_in[6];
    const int*   Mb  = (const int*)d_in[7];
    float* Out = (float*)d_out;

    const int nE = in_sizes[6];   // edges
    const int nN = in_sizes[5];   // nodes

    // ws layout: [cur nN][off nN+1][eidx nE][pad][msg nE*144 f32][pad][Rt NP*16*64*8 bf16]
    int* wsI  = (int*)d_ws;
    int* cur  = wsI;
    int* off  = wsI + nN;
    int* eidx = wsI + 2*nN + 1;
    size_t msgOff = ((size_t)(2*nN + 1 + nE) + 63) & ~(size_t)63;
    float* msg = (float*)d_ws + msgOff;
    size_t rtOff = ((msgOff + (size_t)nE * 144) + 63) & ~(size_t)63;
    unsigned short* Rt = (unsigned short*)((float*)d_ws + rtOff);

    hipMemsetAsync(cur, 0, (size_t)nN * sizeof(int), stream);
    k_count  <<<(nE + BLK - 1) / BLK, BLK, 0, stream>>>(Ma, cur, nE);
    k_scan   <<<1, BLK, 0, stream>>>(cur, off, nN);
    k_scatter<<<(nE + BLK - 1) / BLK, BLK, 0, stream>>>(Ma, cur, eidx, nE);
    k_rt     <<<(NP*16*64*8 + BLK - 1) / BLK, BLK, 0, stream>>>(R, Rt);

    se3_msg   <<<(nE + EPB - 1) / EPB, BLK, 0, stream>>>(F, Ys, Rad, cg, Rt, Mb, msg, nE);
    se3_gather<<<(nN + 15) / 16, BLK, 0, stream>>>(msg, off, eidx, Nn, Out, nN);
}